// Round 4
// baseline (460.002 us; speedup 1.0000x reference)
//
#include <hip/hip_runtime.h>

// GAT self-attention: Wh = h@W; out = softmax(leaky_relu(Wh@Wh^T)) @ Wh
// N=8192, IN_F=256, OUT_F=128. adj input unused by the math.
//
// Round 4: amortize the LDS pipe (the measured bottleneck).
//  - flash: BM 64->128 (each wave owns 32 q-rows, two g-subtiles). K/V
//    fragment reads are tile-data (independent of q-rows), so DS ops per
//    q-row drop 1.77x. launch_bounds(256,2), LDS 54.3KB, NSPLIT=8 ->
//    grid 64x8=512 = exactly 2 blocks/CU, 16 tiles/split exactly.
//  - wh: 64-row blocks + LDS transpose -> WhT16 written as coalesced f16x8
//    (was 1M scalar 2B scattered stores, ~32x write amplification).
// Kept from r3 (verified): swapped QK^T lane-local softmax, reg-held
// prefetch, defer-max, setprio, padded LDS layouts, float4 combine.

#define SEQ   8192
#define DIM   128
#define IN_F  256
#define BM    128
#define BN    64
#define NSPLIT 8
#define NKT   (SEQ / BN)      // 128 key tiles total

typedef __attribute__((ext_vector_type(8))) _Float16 f16x8;
typedef __attribute__((ext_vector_type(4))) _Float16 f16x4;
typedef __attribute__((ext_vector_type(4))) float   floatx4;

// ---------------------------------------------------------------------------
// Kernel 1: Wh = h @ W (fp32 accum) -> Wh16 row-major (coalesced) and WhT16
// via LDS transpose (coalesced f16x8 stores). 128 blocks x 64 rows.
// ---------------------------------------------------------------------------
__global__ __launch_bounds__(256) void wh_kernel(
    const float* __restrict__ h, const float* __restrict__ W,
    _Float16* __restrict__ Wh16, _Float16* __restrict__ WhT16) {
  __shared__ _Float16 T[64 * 132];            // pad 132: transposed reads 8-bank-spread
  int tid = threadIdx.x;
  int cg  = tid & 31;                         // column group: 4 fp32 cols
  int rl  = tid >> 5;                         // 0..7
  int rowbase = blockIdx.x * 64;
  const float4* W4 = (const float4*)W;        // [256][32] of float4
#pragma unroll 2
  for (int sub = 0; sub < 8; sub++) {
    int row = rowbase + sub * 8 + rl;
    const float4* h4 = (const float4*)(h + (size_t)row * IN_F);
    float4 acc = make_float4(0.f, 0.f, 0.f, 0.f);
#pragma unroll 8
    for (int k4 = 0; k4 < IN_F / 4; k4++) {
      float4 hv = h4[k4];
      float4 w0 = W4[(k4 * 4 + 0) * 32 + cg];
      float4 w1 = W4[(k4 * 4 + 1) * 32 + cg];
      float4 w2 = W4[(k4 * 4 + 2) * 32 + cg];
      float4 w3 = W4[(k4 * 4 + 3) * 32 + cg];
      acc.x += hv.x * w0.x + hv.y * w1.x + hv.z * w2.x + hv.w * w3.x;
      acc.y += hv.x * w0.y + hv.y * w1.y + hv.z * w2.y + hv.w * w3.y;
      acc.z += hv.x * w0.z + hv.y * w1.z + hv.z * w2.z + hv.w * w3.z;
      acc.w += hv.x * w0.w + hv.y * w1.w + hv.z * w2.w + hv.w * w3.w;
    }
    f16x4 r;
    r[0] = (_Float16)acc.x; r[1] = (_Float16)acc.y;
    r[2] = (_Float16)acc.z; r[3] = (_Float16)acc.w;
    *(f16x4*)&Wh16[(size_t)row * DIM + cg * 4] = r;
    *(f16x4*)&T[(sub * 8 + rl) * 132 + cg * 4] = r;
  }
  __syncthreads();
  // WhT16[d][rowbase..rowbase+63]: 128 d x 8 row-chunks = 1024 f16x8 chunks.
  // tid&7 = row-chunk, so 8 consecutive lanes write 128B contiguous.
#pragma unroll
  for (int p = 0; p < 4; p++) {
    int chunk = p * 256 + tid;
    int d  = chunk >> 3;
    int rc = chunk & 7;
    f16x8 v;
#pragma unroll
    for (int i = 0; i < 8; i++) v[i] = T[(rc * 8 + i) * 132 + d];
    *(f16x8*)&WhT16[(size_t)d * SEQ + rowbase + rc * 8] = v;
  }
}

// ---------------------------------------------------------------------------
// Kernel 2: flash attention, swapped-QK^T, 32 q-rows per wave (g = 0,1).
// grid = (64 qtiles, 8 splits) = 512 blocks = 2/CU. block = 256 (4 waves).
// LDS: Ksh [64][136] + Vtsh [128][72] + Psh [4][32][72] = 27136 halves.
// ---------------------------------------------------------------------------
__global__ __launch_bounds__(256, 2) void flash_kernel(
    const _Float16* __restrict__ Wh16, const _Float16* __restrict__ WhT16,
    float* __restrict__ Opart, float* __restrict__ mpart,
    float* __restrict__ lpart) {
  __shared__ _Float16 lds[27136];           // 54272 B
  _Float16* Ksh  = lds;                     // 64*136  = 8704 halves
  _Float16* Vtsh = lds + 8704;              // 128*72  = 9216
  _Float16* Psh  = lds + 17920;             // 4*32*72 = 9216

  const int tid  = threadIdx.x;
  const int lane = tid & 63;
  const int wave = tid >> 6;
  const int n16  = lane & 15;
  const int quad = lane >> 4;

  const int qbase  = blockIdx.x * BM + wave * 32;
  const int sp     = blockIdx.y;
  const int jbase0 = sp * (SEQ / NSPLIT);    // 1024 keys per split
  const int jcount = NKT / NSPLIT;           // 16 exactly

  // Q fragments (B operand): qf[g][c] = Q[qbase+g*16+n16][c*32+quad*8+j]
  f16x8 qf[2][4];
#pragma unroll
  for (int g = 0; g < 2; g++)
#pragma unroll
    for (int c = 0; c < 4; c++)
      qf[g][c] = *(const f16x8*)&Wh16[(size_t)(qbase + g * 16 + n16) * DIM
                                      + c * 32 + quad * 8];

  // staging decomposition (identical to r2/r3)
  const int krow = tid >> 4;
  const int kcol = (tid & 15) * 8;
  const int vrow = tid >> 3;
  const int vcol = (tid & 7) * 8;
  f16x8 kreg[4], vreg[4];
  auto stage_load = [&](int jb) {
#pragma unroll
    for (int rep = 0; rep < 4; rep++)
      kreg[rep] = *(const f16x8*)&Wh16[(size_t)(jb + rep * 16 + krow) * DIM + kcol];
#pragma unroll
    for (int rep = 0; rep < 4; rep++)
      vreg[rep] = *(const f16x8*)&WhT16[(size_t)(rep * 32 + vrow) * SEQ + jb + vcol];
  };
  auto stage_write = [&]() {
#pragma unroll
    for (int rep = 0; rep < 4; rep++)
      *(f16x8*)&Ksh[(rep * 16 + krow) * 136 + kcol] = kreg[rep];
#pragma unroll
    for (int rep = 0; rep < 4; rep++)
      *(f16x8*)&Vtsh[(rep * 32 + vrow) * 72 + vcol] = vreg[rep];
  };

  // O^T accumulators: o[g][ct][e] = O[q=qbase+g*16+n16][d=ct*16+quad*4+e]
  floatx4 o[2][8];
#pragma unroll
  for (int g = 0; g < 2; g++)
#pragma unroll
    for (int ct = 0; ct < 8; ct++) o[g][ct] = (floatx4){0.f, 0.f, 0.f, 0.f};
  float m_run[2] = {-1e30f, -1e30f}, l_run[2] = {0.f, 0.f};

  _Float16* Pw = Psh + wave * 2304;          // this wave's 32 x 72 halves

  // prologue: tile 0 staged (latency exposed once)
  stage_load(jbase0);
  stage_write();
  __syncthreads();

  for (int it = 0; it < jcount; it++) {
    // T14: issue next tile's global loads now; ds_write after the
    // post-compute barrier. Latency hides under this tile's compute.
    if (it + 1 < jcount) stage_load(jbase0 + (it + 1) * BN);

    // ---- S^T = K Q^T : s[g][t][e] = S[q=g*16+n16][key=t*16+quad*4+e]
    // kf read once per (t,c), reused for both g — the DS amortization.
    floatx4 s[2][4];
#pragma unroll
    for (int g = 0; g < 2; g++)
#pragma unroll
      for (int t = 0; t < 4; t++) s[g][t] = (floatx4){0.f, 0.f, 0.f, 0.f};
    __builtin_amdgcn_s_setprio(1);
#pragma unroll
    for (int t = 0; t < 4; t++)
#pragma unroll
      for (int c = 0; c < 4; c++) {
        f16x8 kf = *(const f16x8*)&Ksh[(t * 16 + n16) * 136 + c * 32 + quad * 8];
        s[0][t] = __builtin_amdgcn_mfma_f32_16x16x32_f16(kf, qf[0][c], s[0][t], 0, 0, 0);
        s[1][t] = __builtin_amdgcn_mfma_f32_16x16x32_f16(kf, qf[1][c], s[1][t], 0, 0, 0);
      }
    __builtin_amdgcn_s_setprio(0);

    // ---- leaky_relu(0.2) + in-lane max per g, then 2 shfl per g
    float mx[2];
#pragma unroll
    for (int g = 0; g < 2; g++) {
      float m = -1e30f;
#pragma unroll
      for (int t = 0; t < 4; t++)
#pragma unroll
        for (int e = 0; e < 4; e++) {
          float v = s[g][t][e];
          v = v > 0.f ? v : 0.2f * v;
          s[g][t][e] = v;
          m = fmaxf(m, v);
        }
      m = fmaxf(m, __shfl_xor(m, 16, 64));
      m = fmaxf(m, __shfl_xor(m, 32, 64));
      mx[g] = m;
    }

    // T13 defer-max: skip O/l rescale while tile max <= running max + 8.
    float need = fmaxf(mx[0] - m_run[0], mx[1] - m_run[1]);
    if (!__all(need <= 8.f)) {
#pragma unroll
      for (int g = 0; g < 2; g++) {
        float mnew = fmaxf(m_run[g], mx[g]);
        float al   = __expf(m_run[g] - mnew);
        m_run[g] = mnew;
        l_run[g] *= al;
#pragma unroll
        for (int ct = 0; ct < 8; ct++)
#pragma unroll
          for (int e = 0; e < 4; e++) o[g][ct][e] *= al;
      }
    }

    // ---- P = exp(S - m), in-lane row-sum + 2 shfl per g
#pragma unroll
    for (int g = 0; g < 2; g++) {
      float rs = 0.f;
#pragma unroll
      for (int t = 0; t < 4; t++)
#pragma unroll
        for (int e = 0; e < 4; e++) {
          float p = __expf(s[g][t][e] - m_run[g]);
          s[g][t][e] = p;
          rs += p;
        }
      rs += __shfl_xor(rs, 16, 64);
      rs += __shfl_xor(rs, 32, 64);
      l_run[g] += rs;
    }

    // ---- P -> LDS (e-contiguous: b64 x4 per g)
#pragma unroll
    for (int g = 0; g < 2; g++)
#pragma unroll
      for (int t = 0; t < 4; t++) {
        f16x4 pw;
        pw[0] = (_Float16)s[g][t][0]; pw[1] = (_Float16)s[g][t][1];
        pw[2] = (_Float16)s[g][t][2]; pw[3] = (_Float16)s[g][t][3];
        *(f16x4*)&Pw[(g * 16 + n16) * 72 + t * 16 + quad * 4] = pw;
      }
    asm volatile("s_waitcnt lgkmcnt(0)" ::: "memory");
    f16x8 pb[2][2];
#pragma unroll
    for (int g = 0; g < 2; g++)
#pragma unroll
      for (int c = 0; c < 2; c++)
        pb[g][c] = *(const f16x8*)&Pw[(g * 16 + n16) * 72 + c * 32 + quad * 8];

    // ---- O^T += V^T P^T : vf read once per (ct,c), reused for both g
    __builtin_amdgcn_s_setprio(1);
#pragma unroll
    for (int ct = 0; ct < 8; ct++)
#pragma unroll
      for (int c = 0; c < 2; c++) {
        f16x8 vf = *(const f16x8*)&Vtsh[(ct * 16 + n16) * 72 + c * 32 + quad * 8];
        o[0][ct] = __builtin_amdgcn_mfma_f32_16x16x32_f16(vf, pb[0][c], o[0][ct], 0, 0, 0);
        o[1][ct] = __builtin_amdgcn_mfma_f32_16x16x32_f16(vf, pb[1][c], o[1][ct], 0, 0, 0);
      }
    __builtin_amdgcn_s_setprio(0);

    __syncthreads();                       // all waves done reading tile it
    if (it + 1 < jcount) {
      stage_write();                       // compiler inserts vmcnt waits
      __syncthreads();                     // tile it+1 ready
    }
  }

  // ---- write unnormalized partials: coalesced float4 stores
  float* Op = Opart + (size_t)sp * SEQ * DIM;
#pragma unroll
  for (int g = 0; g < 2; g++) {
#pragma unroll
    for (int ct = 0; ct < 8; ct++)
      *(float4*)&Op[(size_t)(qbase + g * 16 + n16) * DIM + ct * 16 + quad * 4] =
          make_float4(o[g][ct][0], o[g][ct][1], o[g][ct][2], o[g][ct][3]);
    if (quad == 0) {
      mpart[sp * SEQ + qbase + g * 16 + n16] = m_run[g];
      lpart[sp * SEQ + qbase + g * 16 + n16] = l_run[g];
    }
  }
}

// ---------------------------------------------------------------------------
// Kernel 3: log-sum-exp combine of NSPLIT partials -> out fp32 (float4/thread)
// ---------------------------------------------------------------------------
__global__ __launch_bounds__(256) void combine_kernel(
    const float* __restrict__ Opart, const float* __restrict__ mpart,
    const float* __restrict__ lpart, float* __restrict__ out) {
  int idx4 = blockIdx.x * 256 + threadIdx.x;   // 0 .. SEQ*DIM/4-1
  int row  = idx4 >> 5;                        // 32 float4 per row
  float M = -1e30f;
#pragma unroll
  for (int p = 0; p < NSPLIT; p++) M = fmaxf(M, mpart[p * SEQ + row]);
  float den = 0.f;
  float4 num = make_float4(0.f, 0.f, 0.f, 0.f);
#pragma unroll
  for (int p = 0; p < NSPLIT; p++) {
    float e = __expf(mpart[p * SEQ + row] - M);
    den += e * lpart[p * SEQ + row];
    float4 v = ((const float4*)Opart)[(size_t)p * (SEQ * DIM / 4) + idx4];
    num.x += e * v.x; num.y += e * v.y; num.z += e * v.z; num.w += e * v.w;
  }
  float inv = 1.f / den;
  ((float4*)out)[idx4] = make_float4(num.x * inv, num.y * inv,
                                     num.z * inv, num.w * inv);
}

// ---------------------------------------------------------------------------
extern "C" void kernel_launch(void* const* d_in, const int* in_sizes, int n_in,
                              void* d_out, int out_size, void* d_ws,
                              size_t ws_size, hipStream_t stream) {
  const float* h = (const float*)d_in[0];
  // d_in[1] = adj  (unused by the reference math)
  const float* W = (const float*)d_in[2];
  float* out = (float*)d_out;

  char* ws = (char*)d_ws;
  _Float16* Wh16  = (_Float16*)ws;                                 // 2 MiB
  _Float16* WhT16 = (_Float16*)(ws + (size_t)2 * 1024 * 1024);     // 2 MiB
  float* Opart = (float*)(ws + (size_t)4 * 1024 * 1024);           // 32 MiB
  float* mpart = (float*)(ws + (size_t)36 * 1024 * 1024);          // 256 KiB
  float* lpart = (float*)(ws + (size_t)36 * 1024 * 1024 + 512 * 1024);

  wh_kernel<<<SEQ / 64, 256, 0, stream>>>(h, W, Wh16, WhT16);
  dim3 grid(SEQ / BM, NSPLIT);
  flash_kernel<<<grid, 256, 0, stream>>>(Wh16, WhT16, Opart, mpart, lpart);
  combine_kernel<<<(SEQ * DIM / 4) / 256, 256, 0, stream>>>(Opart, mpart, lpart, out);
}